// Round 20
// baseline (29.633 us; speedup 1.0000x reference)
//
#include <hip/hip_runtime.h>

// G=14, B=64, T=2048, H=6
#define Gc 14
#define Hc 6
#define NPc (64*2048)          // B*T points
#define LOG_2PI 1.8378770664093453f

__device__ __forceinline__ float frsq(float x){ return __builtin_amdgcn_rsqf(x); }
__device__ __forceinline__ float frcp(float x){ return __builtin_amdgcn_rcpf(x); }

// DPP quad_perm broadcast of lane L's value to all 4 lanes of its quad.
template<int CTRL>
__device__ __forceinline__ float dppf(float x){
    union { float f; int i; } u; u.f = x;
    u.i = __builtin_amdgcn_update_dpp(0, u.i, CTRL, 0xF, 0xF, true);
    return u.f;
}
template<int L>
__device__ __forceinline__ float qbcast(float x){ return dppf<L * 0x55>(x); }

__device__ __forceinline__ void nt_store_f(float* p, float v){
    __builtin_nontemporal_store(v, p);
}

// ---- R20: Householder on the scalar 4-lane quad layout (R19), with the
// register cap loosened one notch: (256,3) -> cap ~85 VGPR. R19's (256,4)
// 64-cap made the allocator spill ~4 floats/thread (WRITE 31 MB, VGPR 48)
// yet still matched R17 -- extra residency paid for the spill tax. 85 cap
// fits the ~76-82 live peak cleanly; VGPR-permitted residency = 6 waves/SIMD.
// Quad layout (1 point = 4 lanes):
//   L0: banks{0,1,2} = cur{0,1,2} | L1: cur{3,4,5} | L2: nxt{0,1,2} | L3: nxt{3,4,5}
//   bank 3 on EVERY lane = b (duplicated x4; rides the uniform update stream).
// Householder per sweep (QR uniqueness => outputs invariant to zeroing scheme):
//   q=||head||^2, rn=||head||, s=copysign(rn,h_pivot), v=head+s*e_pivot,
//   beta=1/(q+s*h_pivot); col -= beta*(v.col)*v ; logC==0 dropped;
//   phase-2 stored row flipped by -sgn(s) (positive-diagonal convention).
template<int L, int B, int N, bool UPD_LAST>
__device__ __forceinline__ float hh_sweep(float (&st)[Gc][4], float* sOut){
    float q0 = 0.f, q1 = 0.f;
    float d0 = 0.f, d1 = 0.f, d2 = 0.f, d3 = 0.f;
    float hl = 0.f;
#pragma unroll
    for (int i = 0; i < N; ++i){
        const float hi = qbcast<L>(st[i][B]);
        if (i & 1) q1 = fmaf(hi, hi, q1); else q0 = fmaf(hi, hi, q0);
        d0 = fmaf(hi, st[i][0], d0);
        d1 = fmaf(hi, st[i][1], d1);
        d2 = fmaf(hi, st[i][2], d2);
        d3 = fmaf(hi, st[i][3], d3);
        if (i == N - 1) hl = hi;
    }
    const float q    = q0 + q1;
    const float rn   = q * frsq(q);              // ||head||
    const float s    = copysignf(rn, hl);
    const float vl   = hl + s;                   // v at pivot (no cancellation)
    const float beta = frcp(fmaf(s, hl, q));     // 1/(q+s*hl) = 2/(v.v)
    // pivot dot fix: v_pivot = hl + s, dots used hl
    d0 = fmaf(s, st[N - 1][0], d0);
    d1 = fmaf(s, st[N - 1][1], d1);
    d2 = fmaf(s, st[N - 1][2], d2);
    d3 = fmaf(s, st[N - 1][3], d3);
    const float t0 = d0 * beta, t1 = d1 * beta, t2 = d2 * beta, t3 = d3 * beta;
    // rank-1 update (broadcast read precedes slot i's writes)
#pragma unroll
    for (int i = 0; i < N - 1; ++i){
        const float hn = -qbcast<L>(st[i][B]);
        st[i][0] = fmaf(t0, hn, st[i][0]);
        st[i][1] = fmaf(t1, hn, st[i][1]);
        st[i][2] = fmaf(t2, hn, st[i][2]);
        st[i][3] = fmaf(t3, hn, st[i][3]);
    }
    if (UPD_LAST){
        st[N - 1][0] = fmaf(t0, -vl, st[N - 1][0]);
        st[N - 1][1] = fmaf(t1, -vl, st[N - 1][1]);
        st[N - 1][2] = fmaf(t2, -vl, st[N - 1][2]);
        st[N - 1][3] = fmaf(t3, -vl, st[N - 1][3]);
    }
    *sOut = s;
    return rn;
}

// (256,3): empirical cap = 256/min_waves ~ 85 VGPR -> no spill for ~80 live,
// VGPR-permitted residency 6 waves/SIMD (vs 4 at 128-cap, spill at 64-cap).
__global__ void __launch_bounds__(256, 3)
gaussmerge_kernel(const float* __restrict__ cur_in,
                  const float* __restrict__ nxt_in,
                  const float* __restrict__ b_in,
                  float* __restrict__ out)
{
    const int tid = threadIdx.x;
    const int l = tid & 3;                          // lane role in quad
    const int p = blockIdx.x * 64 + (tid >> 2);     // point index

    const float* arr  = (l < 2) ? cur_in : nxt_in;
    const float* base = arr + (size_t)p * Hc + ((l & 1) ? 3 : 0);
    const float* bp   = b_in + p;

    float st[Gc][4];
#pragma unroll
    for (int g = 0; g < Gc; ++g){
        const float* rec = base + (size_t)g * (NPc * Hc);
        if (l & 1){   // offset 3 floats: scalar @0 (4-al), float2 @1 (8-al)
            const float  a = rec[0];
            const float2 v = *(const float2*)(rec + 1);
            st[g][0] = a; st[g][1] = v.x; st[g][2] = v.y;
        } else {      // offset 0: float2 @0 (8-al), scalar @2
            const float2 v = *(const float2*)rec;
            st[g][0] = v.x; st[g][1] = v.y; st[g][2] = rec[2];
        }
        st[g][3] = bp[(size_t)g * NPc];   // b duplicated on all 4 lanes
    }

    float LC = 0.0f;    // rn broadcast-derived -> identical on all 4 lanes
    float sdump;

    // ---- phase 1: head = cur[k]; k=0..2 -> L0 bank k, k=3..5 -> L1 bank k-3 ----
    LC -= __logf(hh_sweep<0, 0, 14, false>(st, &sdump));
    LC -= __logf(hh_sweep<0, 1, 13, false>(st, &sdump));
    LC -= __logf(hh_sweep<0, 2, 12, false>(st, &sdump));
    LC -= __logf(hh_sweep<1, 0, 11, false>(st, &sdump));
    LC -= __logf(hh_sweep<1, 1, 10, false>(st, &sdump));
    LC -= __logf(hh_sweep<1, 2,  9, false>(st, &sdump));

    // ---- phase 2: head = nxt[k]; k=0..2 -> L2 bank k, k=3..5 -> L3 bank k-3 ----
    float* outN = out;                               // (6, B, T, H)
    float* outB = out + (size_t)Hc * NPc * Hc;       // (6, B, T)
    float* outL = outB + (size_t)Hc * NPc;           // (B, T)

#define PH2(K, L_, B_, N_)                                                      \
    {                                                                           \
        float s_;                                                               \
        (void)hh_sweep<L_, B_, N_, true>(st, &s_);                              \
        constexpr int m = (N_) - 1;                                             \
        const float flip = -copysignf(1.0f, s_);  /* positive-diag convention */\
        float* o = outN + (size_t)(K) * (NPc * Hc) + (size_t)p * Hc;            \
        if (l == 2){          /* nxt{0,1,2} */                                  \
            nt_store_f(o,     st[m][0] * flip);                                 \
            nt_store_f(o + 1, st[m][1] * flip);                                 \
            nt_store_f(o + 2, st[m][2] * flip);                                 \
        } else if (l == 3){   /* nxt{3,4,5} */                                  \
            nt_store_f(o + 3, st[m][0] * flip);                                 \
            nt_store_f(o + 4, st[m][1] * flip);                                 \
            nt_store_f(o + 5, st[m][2] * flip);                                 \
        } else if (l == 1){   /* kept_b (duplicated bank 3) */                  \
            nt_store_f(outB + (size_t)(K) * NPc + p, st[m][3] * flip);          \
        }                                                                       \
    }

    PH2(0, 2, 0, 8)
    PH2(1, 2, 1, 7)
    PH2(2, 2, 2, 6)
    PH2(3, 3, 0, 5)
    PH2(4, 3, 1, 4)
    PH2(5, 3, 2, 3)
#undef PH2

    // ---- epilogue: residual biases (slots 0,1) local in bank 3 on every lane ----
    LC += -0.5f * (LOG_2PI + st[0][3] * st[0][3]);
    LC += -0.5f * (LOG_2PI + st[1][3] * st[1][3]);
    if (l == 0) nt_store_f(outL + p, LC);
}

extern "C" void kernel_launch(void* const* d_in, const int* in_sizes, int n_in,
                              void* d_out, int out_size, void* d_ws, size_t ws_size,
                              hipStream_t stream) {
    const float* cur = (const float*)d_in[0];
    const float* nxt = (const float*)d_in[1];
    const float* bia = (const float*)d_in[2];
    float* out = (float*)d_out;

    // 4 threads per point: 256-thread blocks cover 64 points each.
    dim3 grid((NPc * 4) / 256), block(256);
    gaussmerge_kernel<<<grid, block, 0, stream>>>(cur, nxt, bia, out);
}

// Round 21
// 29.318 us; speedup vs baseline: 1.0107x; 1.0107x over previous
//
#include <hip/hip_runtime.h>

// G=14, B=64, T=2048, H=6
#define Gc 14
#define Hc 6
#define NPc (64*2048)          // B*T points
#define LOG_2PI 1.8378770664093453f

typedef float v2f __attribute__((ext_vector_type(2)));

__device__ __forceinline__ float frsq(float x){ return __builtin_amdgcn_rsqf(x); }
__device__ __forceinline__ float frcp(float x){ return __builtin_amdgcn_rcpf(x); }

// DPP quad_perm broadcast within lane pairs (1-cycle VALU, no LDS):
//   0xA0 = [0,0,2,2] -> pair gets EVEN lane's value; 0xF5 = [1,1,3,3] -> ODD lane's.
template<int CTRL>
__device__ __forceinline__ float dppf(float x){
    union { float f; int i; } u; u.f = x;
    u.i = __builtin_amdgcn_update_dpp(0, u.i, CTRL, 0xF, 0xF, true);
    return u.f;
}
template<int OQ>
__device__ __forceinline__ float bcast(float x){
    return (OQ == 0) ? dppf<0xA0>(x) : dppf<0xF5>(x);
}

__device__ __forceinline__ void nt_store_v2f(float* p, v2f v){
    union { v2f f; unsigned long long u; } c; c.f = v;
    __builtin_nontemporal_store(c.u, (unsigned long long*)p);
}

// ---- Householder sweep (R17 = session best, 28.46 us) ----
// The reference's 90 chained 2x2 gprods are EXACT orthogonal rotations
// (rows orthonormal; hence logC == 0). Phase 1 is a Givens-QR of the cur
// block (positive diagonal), phase 2 a QR of the residual nxt block. By QR
// uniqueness (positive diag), outputs are invariant to the zeroing scheme ->
// ONE Householder reflector per sweep:
//   q = ||head||^2, rn = ||head||, s = copysign(rn, h_pivot), v = head + s*e_pivot
//   beta = 1/(q + s*h_pivot);  col -= beta*(v.col) * v
// Pivot slot = N-1 (the reference's pop slot). Phase-2 stored row is flipped
// by -sgn(s) to restore the positive-diagonal sign convention.
// Lane0 holds cur banks, lane1 nxt banks; bb duplicated (bit-identical).
template<int J, int C, int N, int OQ, bool UPD_LAST>
__device__ __forceinline__ float hh_sweep(v2f (&st)[Gc][3], float (&bb)[Gc], float* sOut){
    // pass A: broadcast heads; accumulate q (2-way) and 7 column dots
    float q0 = 0.f, q1 = 0.f;
    v2f d0 = {0.f, 0.f}, d1 = {0.f, 0.f}, d2 = {0.f, 0.f};
    float db = 0.f;
    float hl = 0.f;
#pragma unroll
    for (int i = 0; i < N; ++i){
        const float hi = bcast<OQ>(st[i][J][C]);
        if (i & 1) q1 = fmaf(hi, hi, q1); else q0 = fmaf(hi, hi, q0);
        const v2f H = {hi, hi};
        d0 = __builtin_elementwise_fma(H, st[i][0], d0);
        d1 = __builtin_elementwise_fma(H, st[i][1], d1);
        d2 = __builtin_elementwise_fma(H, st[i][2], d2);
        db = fmaf(hi, bb[i], db);
        if (i == N - 1) hl = hi;
    }
    const float q    = q0 + q1;
    const float rn   = q * frsq(q);              // ||head||
    const float s    = copysignf(rn, hl);
    const float vl   = hl + s;                   // v at pivot (no cancellation)
    const float beta = frcp(fmaf(s, hl, q));     // 1/(q + s*hl) = 2/(v.v)
    // dot fix for pivot (v_pivot = hl + s, dots used hl): d += s * c[N-1]
    {
        const v2f S2 = {s, s};
        d0 = __builtin_elementwise_fma(S2, st[N - 1][0], d0);
        d1 = __builtin_elementwise_fma(S2, st[N - 1][1], d1);
        d2 = __builtin_elementwise_fma(S2, st[N - 1][2], d2);
        db = fmaf(s, bb[N - 1], db);
    }
    const v2f B2 = {beta, beta};
    const v2f t0 = d0 * B2, t1 = d1 * B2, t2 = d2 * B2;
    const float tb = db * beta;
    // pass B: rank-1 update c_i -= t * h_i (broadcast precedes slot i's writes)
#pragma unroll
    for (int i = 0; i < N - 1; ++i){
        const float hi = bcast<OQ>(st[i][J][C]);
        const v2f Hn = {-hi, -hi};
        st[i][0] = __builtin_elementwise_fma(t0, Hn, st[i][0]);
        st[i][1] = __builtin_elementwise_fma(t1, Hn, st[i][1]);
        st[i][2] = __builtin_elementwise_fma(t2, Hn, st[i][2]);
        bb[i] = fmaf(tb, -hi, bb[i]);
    }
    if (UPD_LAST){   // pivot slot needed only when it is stored (phase 2)
        const v2f Vn = {-vl, -vl};
        st[N - 1][0] = __builtin_elementwise_fma(t0, Vn, st[N - 1][0]);
        st[N - 1][1] = __builtin_elementwise_fma(t1, Vn, st[N - 1][1]);
        st[N - 1][2] = __builtin_elementwise_fma(t2, Vn, st[N - 1][2]);
        bb[N - 1] = fmaf(tb, -vl, bb[N - 1]);
    }
    *sOut = s;
    return rn;
}

// (256,2): empirical cap = 256/min_waves = 128 VGPR (proven no-spill tier;
// VGPR 76, 4 waves/SIMD). 64/85-cap variants (R19/R20) spill ~9 MB and lose.
__global__ void __launch_bounds__(256, 2)
gaussmerge_kernel(const float* __restrict__ cur_in,
                  const float* __restrict__ nxt_in,
                  const float* __restrict__ b_in,
                  float* __restrict__ out)
{
    const int tid = threadIdx.x;
    const int q = tid & 1;                          // 0: cur-owner, 1: nxt-owner
    const int p = blockIdx.x * 128 + (tid >> 1);    // point index

    v2f   st[Gc][3];
    float bb[Gc];

    const float* abase = (q ? nxt_in : cur_in) + (size_t)p * Hc;
    const float* bp    = b_in + p;
#pragma unroll
    for (int g = 0; g < Gc; ++g){
        const float* rec = abase + (size_t)g * (NPc * Hc);
        const float4 A = *(const float4*)rec;
        const float2 B = *(const float2*)(rec + 4);
        st[g][0] = (v2f){A.x, A.y};
        st[g][1] = (v2f){A.z, A.w};
        st[g][2] = (v2f){B.x, B.y};
        bb[g] = bp[(size_t)g * NPc];
    }

    float LC = 0.0f;   // rn broadcast-derived -> identical on both lanes
    float sdump;

    // ---- phase 1: head = cur[k] on lane0; (J,C) = (k>>1, k&1); N = 14-k ----
    LC -= __logf(hh_sweep<0, 0, 14, 0, false>(st, bb, &sdump));
    LC -= __logf(hh_sweep<0, 1, 13, 0, false>(st, bb, &sdump));
    LC -= __logf(hh_sweep<1, 0, 12, 0, false>(st, bb, &sdump));
    LC -= __logf(hh_sweep<1, 1, 11, 0, false>(st, bb, &sdump));
    LC -= __logf(hh_sweep<2, 0, 10, 0, false>(st, bb, &sdump));
    LC -= __logf(hh_sweep<2, 1,  9, 0, false>(st, bb, &sdump));

    // ---- phase 2: head = nxt[k] on lane1; N = 8-k; pivot slot m = N-1 ----
    float* outN = out;                               // (6, B, T, H)
    float* outB = out + (size_t)Hc * NPc * Hc;       // (6, B, T)
    float* outL = outB + (size_t)Hc * NPc;           // (B, T)

#define PH2(K, J, C, N)                                                         \
    {                                                                           \
        float s_;                                                               \
        (void)hh_sweep<J, C, N, 1, true>(st, bb, &s_);                          \
        constexpr int m = (N) - 1;                                              \
        const float flip = -copysignf(1.0f, s_);  /* positive-diag convention */\
        const v2f F = {flip, flip};                                             \
        if (q) {                                                                \
            float* o = outN + (size_t)(K) * (NPc * Hc) + (size_t)p * Hc;        \
            nt_store_v2f(o,     st[m][0] * F);                                  \
            nt_store_v2f(o + 2, st[m][1] * F);                                  \
            nt_store_v2f(o + 4, st[m][2] * F);                                  \
        } else {                                                                \
            __builtin_nontemporal_store(bb[m] * flip,                           \
                                        outB + (size_t)(K) * NPc + p);          \
        }                                                                       \
    }

    PH2(0, 0, 0, 8)
    PH2(1, 0, 1, 7)
    PH2(2, 1, 0, 6)
    PH2(3, 1, 1, 5)
    PH2(4, 2, 0, 4)
    PH2(5, 2, 1, 3)
#undef PH2

    // ---- epilogue: residual biases (slots 0,1; identical on both lanes) ----
    LC += -0.5f * (LOG_2PI + bb[0] * bb[0]);
    LC += -0.5f * (LOG_2PI + bb[1] * bb[1]);
    if (q == 0) __builtin_nontemporal_store(LC, outL + p);
}

extern "C" void kernel_launch(void* const* d_in, const int* in_sizes, int n_in,
                              void* d_out, int out_size, void* d_ws, size_t ws_size,
                              hipStream_t stream) {
    const float* cur = (const float*)d_in[0];
    const float* nxt = (const float*)d_in[1];
    const float* bia = (const float*)d_in[2];
    float* out = (float*)d_out;

    // 2 threads per point: 256-thread blocks cover 128 points each.
    dim3 grid((NPc * 2) / 256), block(256);
    gaussmerge_kernel<<<grid, block, 0, stream>>>(cur, nxt, bia, out);
}